// Round 3
// baseline (18924.854 us; speedup 1.0000x reference)
//
#include <hip/hip_runtime.h>
#include <hip/hip_cooperative_groups.h>
#include <math.h>

namespace cg = cooperative_groups;

// Round 3: single persistent cooperative kernel for the full 64-step rollout.
// 256 blocks x 512 threads (1 block/CU, 2 waves/SIMD). 4 grid syncs per step.
// W_hh gates for step t+1 overlap the sample phase of step t.
// Pre-split bf16 hi/lo weights as round 2; per-row accumulation order identical.

#define EMBD 512
#define HIDD 1024
#define NVOC 32000
#define SEQL 64
#define NLB  250     // 32000/128 logits tiles

typedef unsigned int   uint32;
typedef unsigned short u16;
typedef __attribute__((ext_vector_type(8))) short bf16x8;
typedef __attribute__((ext_vector_type(4))) float f32x4;

// ---- fp32 -> (bf16 hi RNE, bf16 lo) split ------------------------------
__device__ __forceinline__ void split_pair(float x, float y, uint32& hi, uint32& lo) {
    uint32 a = __float_as_uint(x), b = __float_as_uint(y);
    uint32 ra = a + 0x7fffu + ((a >> 16) & 1u);
    uint32 rb = b + 0x7fffu + ((b >> 16) & 1u);
    hi = (ra >> 16) | (rb & 0xffff0000u);
    float lx = x - __uint_as_float(ra & 0xffff0000u);
    float ly = y - __uint_as_float(rb & 0xffff0000u);
    lo = (__float_as_uint(lx) >> 16) | (__float_as_uint(ly) & 0xffff0000u);
}

__device__ __forceinline__ void split8(const float4 f0, const float4 f1,
                                       bf16x8& hi, bf16x8& lo) {
    union { bf16x8 v; uint32 u[4]; } H, L;
    split_pair(f0.x, f0.y, H.u[0], L.u[0]);
    split_pair(f0.z, f0.w, H.u[1], L.u[1]);
    split_pair(f1.x, f1.y, H.u[2], L.u[2]);
    split_pair(f1.z, f1.w, H.u[3], L.u[3]);
    hi = H.v; lo = L.v;
}

__device__ __forceinline__ void split_scalar(float f, u16& hi, u16& lo) {
    uint32 u = __float_as_uint(f);
    uint32 r = u + 0x7fffu + ((u >> 16) & 1u);
    hi = (u16)(r >> 16);
    float lf = f - __uint_as_float(r & 0xffff0000u);
    uint32 ul = __float_as_uint(lf);
    uint32 rl = ul + 0x7fffu + ((ul >> 16) & 1u);
    lo = (u16)(rl >> 16);
}

// ---- B fragments: lane l holds B[k=(l>>4)*8+e][col=l&15], stored [b][K] --
__device__ __forceinline__ void load_b4(const u16* __restrict__ Bh,
                                        const u16* __restrict__ Bl,
                                        int K, int kk, int ll,
                                        bf16x8* bh, bf16x8* bl) {
#pragma unroll
    for (int tc = 0; tc < 4; ++tc) {
        size_t off = (size_t)(tc * 16 + ll) * K + kk;
        bh[tc] = *(const bf16x8*)(Bh + off);
        bl[tc] = *(const bf16x8*)(Bl + off);
    }
}

// D += Ahi*Bhi + Ahi*Blo + Alo*Bhi over 4 col tiles
__device__ __forceinline__ void mfma3x4(const bf16x8 ahi, const bf16x8 alo,
                                        const bf16x8* bh, const bf16x8* bl,
                                        f32x4* acc) {
#pragma unroll
    for (int tc = 0; tc < 4; ++tc)
        acc[tc] = __builtin_amdgcn_mfma_f32_16x16x32_bf16(ahi, bh[tc], acc[tc], 0, 0, 0);
#pragma unroll
    for (int tc = 0; tc < 4; ++tc)
        acc[tc] = __builtin_amdgcn_mfma_f32_16x16x32_bf16(ahi, bl[tc], acc[tc], 0, 0, 0);
#pragma unroll
    for (int tc = 0; tc < 4; ++tc)
        acc[tc] = __builtin_amdgcn_mfma_f32_16x16x32_bf16(alo, bh[tc], acc[tc], 0, 0, 0);
}

// ---- weight pre-split into MFMA-lane-linear tiles ----------------------
__global__ __launch_bounds__(256) void k_split_w(const float* __restrict__ W,
                                                 u16* __restrict__ hi,
                                                 u16* __restrict__ lo,
                                                 int K, int kol2, int total) {
    int idx = blockIdx.x * 256 + threadIdx.x;
    if (idx >= total) return;
    int row = idx >> kol2;
    int ko  = idx & ((1 << kol2) - 1);
    const float* src = W + (size_t)row * K + ko * 8;
    float4 f0 = *(const float4*)src;
    float4 f1 = *(const float4*)(src + 4);
    union { bf16x8 v; uint32 u[4]; } H, L;
    split_pair(f0.x, f0.y, H.u[0], L.u[0]);
    split_pair(f0.z, f0.w, H.u[1], L.u[1]);
    split_pair(f1.x, f1.y, H.u[2], L.u[2]);
    split_pair(f1.z, f1.w, H.u[3], L.u[3]);
    int tile = row >> 4, chunk = ko >> 2;
    int lane = ((ko & 3) << 4) | (row & 15);
    size_t off = ((size_t)tile * (K >> 5) + chunk) * 512 + lane * 8;
    *(bf16x8*)(hi + off) = H.v;
    *(bf16x8*)(lo + off) = L.v;
}

// ---- pipelined GEMM, 1 row-tile (16 rows) x 64 cols, K = NC*32 ---------
template<int NC, bool PS>
__device__ __forceinline__ void gemm_rt1(
    const u16* __restrict__ ah_base, const u16* __restrict__ al_base,
    const float* __restrict__ wrow,
    const u16* __restrict__ bh, const u16* __restrict__ bl,
    int K, int l, int lg, int ll, f32x4* acc) {
    bf16x8 AH[4], AL[4];
    float4 F0[4], F1[4];
    bf16x8 BH[2][4], BL[2][4];
    const int la = l * 8, kl = lg * 8;
#define LA1(c, s) do { if constexpr (PS) { \
        AH[s] = *(const bf16x8*)(ah_base + (size_t)(c) * 512 + la); \
        AL[s] = *(const bf16x8*)(al_base + (size_t)(c) * 512 + la); \
    } else { \
        F0[s] = *(const float4*)(wrow + (c) * 32 + kl); \
        F1[s] = *(const float4*)(wrow + (c) * 32 + kl + 4); } } while (0)
    LA1(0, 0); load_b4(bh, bl, K, kl, ll, BH[0], BL[0]); LA1(1, 1);
#pragma unroll 4
    for (int c = 0; c < NC; ++c) {
        if (c + 1 < NC) load_b4(bh, bl, K, (c + 1) * 32 + kl, ll, BH[(c + 1) & 1], BL[(c + 1) & 1]);
        if (c + 2 < NC) LA1(c + 2, (c + 2) & 3);
        bf16x8 ah, al;
        if constexpr (PS) { ah = AH[c & 3]; al = AL[c & 3]; }
        else split8(F0[c & 3], F1[c & 3], ah, al);
        mfma3x4(ah, al, BH[c & 1], BL[c & 1], acc);
    }
#undef LA1
}

// ---- args bundle -------------------------------------------------------
struct RollArgs {
    const float* emb; const float* w_ih; const float* w_hh;
    const float* b_ih; const float* b_hh; const float* w_out; const float* b_out;
    const float* gum; const float* eps;
    const u16* wihhi; const u16* wihlo; const u16* whhhi; const u16* whhlo;
    const u16* wohi; const u16* wolo;
    float* H0; float* H1; float* GI; float* GH;
    float* PM; float* PSUM; float* AS_; int* AI; float* AL;
    u16* HSH0; u16* HSL0; u16* HSH1; u16* HSL1;
    u16* XHI; u16* XLO; float* out;
};

// ---- phases ------------------------------------------------------------
template<bool PS>
__device__ __forceinline__ void phase_ih(const RollArgs& a, int tile,
                                         int l, int lg, int ll) {
    f32x4 acc[4] = {};
    gemm_rt1<16, PS>(a.wihhi + (size_t)tile * 8192, a.wihlo + (size_t)tile * 8192,
                     a.w_ih + (size_t)(tile * 16 + ll) * EMBD,
                     a.XHI, a.XLO, EMBD, l, lg, ll, acc);
#pragma unroll
    for (int j = 0; j < 4; ++j) {
        int n = tile * 16 + lg * 4 + j;
        float bi = a.b_ih[n];
#pragma unroll
        for (int tc = 0; tc < 4; ++tc)
            a.GI[n * 64 + tc * 16 + ll] = acc[tc][j] + bi;
    }
}

template<bool PS>
__device__ __forceinline__ void phase_hh(const RollArgs& a, int tile,
                                         const u16* __restrict__ bh,
                                         const u16* __restrict__ bl,
                                         int l, int lg, int ll) {
    f32x4 acc[4] = {};
    gemm_rt1<32, PS>(a.whhhi + (size_t)tile * 16384, a.whhlo + (size_t)tile * 16384,
                     a.w_hh + (size_t)(tile * 16 + ll) * HIDD,
                     bh, bl, HIDD, l, lg, ll, acc);
#pragma unroll
    for (int j = 0; j < 4; ++j) {
        int n = tile * 16 + lg * 4 + j;
        float bi = a.b_hh[n];
#pragma unroll
        for (int tc = 0; tc < 4; ++tc)
            a.GH[n * 64 + tc * 16 + ll] = acc[tc][j] + bi;
    }
}

__device__ __forceinline__ void phase_gru(const RollArgs& a, int j, int b,
                                          const float* __restrict__ h_in,
                                          float* __restrict__ h_out,
                                          u16* __restrict__ hh_out,
                                          u16* __restrict__ hl_out) {
    float ir = a.GI[j * 64 + b], iz = a.GI[(j + 1024) * 64 + b], in_ = a.GI[(j + 2048) * 64 + b];
    float hr = a.GH[j * 64 + b], hz = a.GH[(j + 1024) * 64 + b], hn = a.GH[(j + 2048) * 64 + b];
    float h = h_in[b * HIDD + j];
    float r = 1.f / (1.f + expf(-(ir + hr)));
    float z = 1.f / (1.f + expf(-(iz + hz)));
    float n = tanhf(in_ + r * hn);
    float hnew = (1.f - z) * n + z * h;
    h_out[b * HIDD + j] = hnew;
    u16 h_, l_; split_scalar(hnew, h_, l_);
    hh_out[b * HIDD + j] = h_; hl_out[b * HIDD + j] = l_;
}

template<bool PS>
__device__ __forceinline__ void phase_logits(const RollArgs& a, int bx, int tid, int t,
                                             const u16* __restrict__ hh,
                                             const u16* __restrict__ hl) {
    const int wv = tid >> 6, l = tid & 63, lg = l >> 4, ll = l & 15;
    const int rb = bx * 128 + wv * 16;
    f32x4 acc[4] = {};
    gemm_rt1<32, PS>(a.wohi + (size_t)(rb >> 4) * 16384, a.wolo + (size_t)(rb >> 4) * 16384,
                     a.w_out + (size_t)(rb + ll) * HIDD, hh, hl, HIDD, l, lg, ll, acc);

    float val[4][4];   // [tc][j]: row rb+lg*4+j, col(b) tc*16+ll
#pragma unroll
    for (int j = 0; j < 4; ++j) {
        float bo = a.b_out[rb + lg * 4 + j];
#pragma unroll
        for (int tc = 0; tc < 4; ++tc) val[tc][j] = acc[tc][j] + bo;
    }

    bool draw[4]; float4 g4[4];
#pragma unroll
    for (int tc = 0; tc < 4; ++tc) {
        int b = tc * 16 + ll;
        draw[tc] = a.eps[t * 64 + b] <= 0.5f;
        g4[tc] = *(const float4*)(a.gum + ((size_t)t * 64 + b) * NVOC + rb + lg * 4);
    }

    __shared__ float sred[8][64];
    __shared__ float sred2[8][64];
    __shared__ int   sredi[8][64];
    __shared__ float sbm[64];

    float lm[4];
#pragma unroll
    for (int tc = 0; tc < 4; ++tc) {
        float m = val[tc][0];
#pragma unroll
        for (int j = 1; j < 4; ++j) m = fmaxf(m, val[tc][j]);
        m = fmaxf(m, __shfl_xor(m, 16));
        m = fmaxf(m, __shfl_xor(m, 32));
        lm[tc] = m;
    }
    if (l < 16) {
#pragma unroll
        for (int tc = 0; tc < 4; ++tc) sred[wv][tc * 16 + l] = lm[tc];
    }
    __syncthreads();
    if (tid < 64) {
        float m = sred[0][tid];
#pragma unroll
        for (int r = 1; r < 8; ++r) m = fmaxf(m, sred[r][tid]);
        sbm[tid] = m;
        a.PM[bx * 64 + tid] = m;
    }
    __syncthreads();

#pragma unroll
    for (int tc = 0; tc < 4; ++tc) {
        float bm = sbm[tc * 16 + ll];
        float s = 0.f;
#pragma unroll
        for (int j = 0; j < 4; ++j) s += expf(val[tc][j] - bm);
        s += __shfl_xor(s, 16);
        s += __shfl_xor(s, 32);
        lm[tc] = s;
    }
    if (l < 16) {
#pragma unroll
        for (int tc = 0; tc < 4; ++tc) sred[wv][tc * 16 + l] = lm[tc];
    }
    __syncthreads();
    if (tid < 64) {
        float s = sred[0][tid];
#pragma unroll
        for (int r = 1; r < 8; ++r) s += sred[r][tid];
        a.PSUM[bx * 64 + tid] = s;
    }

    const float LOGV = logf(32000.0f);
    float bsc[4]; int bix[4]; float blg[4];
#pragma unroll
    for (int tc = 0; tc < 4; ++tc) {
        float bs = -INFINITY; int bi = 0x7fffffff; float bl = 0.f;
        const float* gp = (const float*)&g4[tc];
#pragma unroll
        for (int j = 0; j < 4; ++j) {
            float u = fminf(fmaxf(gp[j], 1e-12f), 1.0f);
            float g = -logf(-logf(u));
            float sc = draw[tc] ? (g - LOGV) : (val[tc][j] + g);
            if (sc > bs) { bs = sc; bi = rb + lg * 4 + j; bl = val[tc][j]; }
        }
#pragma unroll
        for (int m2 = 16; m2 <= 32; m2 <<= 1) {
            float os = __shfl_xor(bs, m2);
            int   oi = __shfl_xor(bi, m2);
            float ol = __shfl_xor(bl, m2);
            if (os > bs || (os == bs && oi < bi)) { bs = os; bi = oi; bl = ol; }
        }
        bsc[tc] = bs; bix[tc] = bi; blg[tc] = bl;
    }
    __syncthreads();
    if (l < 16) {
#pragma unroll
        for (int tc = 0; tc < 4; ++tc) {
            sred[wv][tc * 16 + l]  = bsc[tc];
            sredi[wv][tc * 16 + l] = bix[tc];
            sred2[wv][tc * 16 + l] = blg[tc];
        }
    }
    __syncthreads();
    if (tid < 64) {
        float bs = sred[0][tid]; int bi = sredi[0][tid]; float bl = sred2[0][tid];
#pragma unroll
        for (int r = 1; r < 8; ++r) {
            float os = sred[r][tid]; int oi = sredi[r][tid];
            if (os > bs || (os == bs && oi < bi)) { bs = os; bi = oi; bl = sred2[r][tid]; }
        }
        a.AS_[bx * 64 + tid] = bs;
        a.AI[bx * 64 + tid]  = bi;
        a.AL[bx * 64 + tid]  = bl;
    }
}

__device__ __forceinline__ void phase_sample(const RollArgs& a, int b, int tid, int t) {
    __shared__ float sv[512];
    __shared__ int   si_[512];
    __shared__ float sl[512];

    float m = (tid < NLB) ? a.PM[tid * 64 + b] : -INFINITY;
    sv[tid] = m; __syncthreads();
    for (int s = 256; s > 0; s >>= 1) {
        if (tid < s) sv[tid] = fmaxf(sv[tid], sv[tid + s]);
        __syncthreads();
    }
    float M = sv[0]; __syncthreads();

    float ssum = (tid < NLB) ? a.PSUM[tid * 64 + b] * expf(a.PM[tid * 64 + b] - M) : 0.f;
    sv[tid] = ssum; __syncthreads();
    for (int s = 256; s > 0; s >>= 1) {
        if (tid < s) sv[tid] += sv[tid + s];
        __syncthreads();
    }
    float lse = M + logf(sv[0]); __syncthreads();

    float bs = -INFINITY; int bi = 0x7fffffff; float bl = 0.f;
    if (tid < NLB) { bs = a.AS_[tid * 64 + b]; bi = a.AI[tid * 64 + b]; bl = a.AL[tid * 64 + b]; }
    sv[tid] = bs; si_[tid] = bi; sl[tid] = bl; __syncthreads();
    for (int s = 256; s > 0; s >>= 1) {
        if (tid < s) {
            float ov = sv[tid + s]; int oi = si_[tid + s];
            if (ov > sv[tid] || (ov == sv[tid] && oi < si_[tid])) {
                sv[tid] = ov; si_[tid] = oi; sl[tid] = sl[tid + s];
            }
        }
        __syncthreads();
    }
    int sampled = si_[0];
    if (tid == 0) {
        const float LOGV = logf(32000.0f);
        float lp = sl[0] - lse;
        bool draw = a.eps[t * 64 + b] <= 0.5f;
        float bsv = draw ? -LOGV : lp;
        float off = fminf(fmaxf(expf(bsv), 0.001f), 1.0f);
        a.out[b * SEQL + t] = (float)sampled;
        a.out[4096 + b * SEQL + t] = expf(lp) / off;
        a.out[8192 + b * SEQL + t] = lp;
    }
    const float* er = a.emb + (size_t)sampled * EMBD;
    for (int k = tid; k < EMBD; k += 512) {
        u16 h_, l_; split_scalar(er[k], h_, l_);
        a.XHI[b * EMBD + k] = h_; a.XLO[b * EMBD + k] = l_;
    }
}

__device__ __forceinline__ void init_body(const RollArgs& a, int b, int tid, int stride) {
    for (int j = tid; j < HIDD; j += stride) {
        a.H0[b * HIDD + j] = 0.f; a.HSH0[b * HIDD + j] = 0; a.HSL0[b * HIDD + j] = 0;
    }
    for (int k = tid; k < EMBD; k += stride) {
        u16 h_, l_; split_scalar(a.emb[k], h_, l_);
        a.XHI[b * EMBD + k] = h_; a.XLO[b * EMBD + k] = l_;
    }
}

// ---- persistent cooperative kernel -------------------------------------
template<bool PS>
__global__ __launch_bounds__(512, 2) void k_roll(RollArgs a) {
    const int tid = threadIdx.x, bx = blockIdx.x;
    const int wv = tid >> 6, l = tid & 63, lg = l >> 4, ll = l & 15;
    const int gw = bx * 8 + wv;           // 0..2047
    cg::grid_group grid = cg::this_grid();

    if (bx < 64) init_body(a, bx, tid, 512);
    grid.sync();

    for (int t = 0; t < SEQL; ++t) {
        const int hi_ = t & 1, ho_ = hi_ ^ 1;
        const u16* hh_in = hi_ ? a.HSH1 : a.HSH0;
        const u16* hl_in = hi_ ? a.HSL1 : a.HSL0;
        u16* hh_out = ho_ ? a.HSH1 : a.HSH0;
        u16* hl_out = ho_ ? a.HSL1 : a.HSL0;
        const float* h_in = hi_ ? a.H1 : a.H0;
        float* h_out = ho_ ? a.H1 : a.H0;

        // G: ih gates (x_t). hh gates only at t==0 (otherwise done in prior S).
        if (gw < 192) phase_ih<PS>(a, gw, l, lg, ll);
        else if (t == 0 && gw >= 1024 && gw < 1216)
            phase_hh<PS>(a, gw - 1024, hh_in, hl_in, l, lg, ll);
        grid.sync();

        // R: GRU elementwise, wave gw -> j=gw, lane -> b
        if (gw < 1024) phase_gru(a, gw, l, h_in, h_out, hh_out, hl_out);
        grid.sync();

        // L: logits + fused partials
        if (bx < NLB) phase_logits<PS>(a, bx, tid, t, hh_out, hl_out);
        grid.sync();

        // S: final sample (blocks 0..63) || hh gates for t+1 (blocks 64..87)
        if (bx < 64) phase_sample(a, bx, tid, t);
        else if (t + 1 < SEQL && gw >= 512 && gw < 704)
            phase_hh<PS>(a, gw - 512, hh_out, hl_out, l, lg, ll);
        grid.sync();
    }
}

// ---- fallback wrappers (non-cooperative path) --------------------------
__global__ __launch_bounds__(512, 2) void k_init_f(RollArgs a) {
    init_body(a, blockIdx.x, threadIdx.x, 512);
}
template<bool PS>
__global__ __launch_bounds__(512, 2) void k_gates_f(RollArgs a, int hi_) {
    const int tid = threadIdx.x, wv = tid >> 6, l = tid & 63, lg = l >> 4, ll = l & 15;
    const int gw = blockIdx.x * 8 + wv;   // grid 48 -> 0..383
    const u16* hh_in = hi_ ? a.HSH1 : a.HSH0;
    const u16* hl_in = hi_ ? a.HSL1 : a.HSL0;
    if (gw < 192) phase_ih<PS>(a, gw, l, lg, ll);
    else phase_hh<PS>(a, gw - 192, hh_in, hl_in, l, lg, ll);
}
__global__ __launch_bounds__(512, 2) void k_gru_f(RollArgs a, int hi_) {
    const int tid = threadIdx.x, wv = tid >> 6, l = tid & 63;
    const int gw = blockIdx.x * 8 + wv;   // grid 128 -> 0..1023
    const int ho_ = hi_ ^ 1;
    const float* h_in = hi_ ? a.H1 : a.H0;
    float* h_out = ho_ ? a.H1 : a.H0;
    u16* hh_out = ho_ ? a.HSH1 : a.HSH0;
    u16* hl_out = ho_ ? a.HSL1 : a.HSL0;
    if (gw < 1024) phase_gru(a, gw, l, h_in, h_out, hh_out, hl_out);
}
template<bool PS>
__global__ __launch_bounds__(512, 2) void k_logits_f(RollArgs a, int t, int ho_) {
    const u16* hh = ho_ ? a.HSH1 : a.HSH0;
    const u16* hl = ho_ ? a.HSL1 : a.HSL0;
    phase_logits<PS>(a, blockIdx.x, threadIdx.x, t, hh, hl);
}
__global__ __launch_bounds__(512, 2) void k_sample_f(RollArgs a, int t) {
    phase_sample(a, blockIdx.x, threadIdx.x, t);
}

extern "C" void kernel_launch(void* const* d_in, const int* in_sizes, int n_in,
                              void* d_out, int out_size, void* d_ws, size_t ws_size,
                              hipStream_t stream) {
    char* w8 = (char*)d_ws;

    RollArgs a;
    a.emb   = (const float*)d_in[0];
    a.w_ih  = (const float*)d_in[1];
    a.w_hh  = (const float*)d_in[2];
    a.b_ih  = (const float*)d_in[3];
    a.b_hh  = (const float*)d_in[4];
    a.w_out = (const float*)d_in[5];
    a.b_out = (const float*)d_in[6];
    a.gum   = (const float*)d_in[7];
    a.eps   = (const float*)d_in[8];
    a.out   = (float*)d_out;

    a.H0   = (float*)(w8 + 0);
    a.H1   = (float*)(w8 + 262144);
    a.GI   = (float*)(w8 + 524288);
    a.GH   = (float*)(w8 + 1310720);
    a.PM   = (float*)(w8 + 2097152);
    a.PSUM = (float*)(w8 + 2162688);
    a.AS_  = (float*)(w8 + 2228224);
    a.AL   = (float*)(w8 + 2293760);
    a.AI   = (int*)  (w8 + 2359296);
    a.HSH0 = (u16*)(w8 + 2424832);
    a.HSL0 = (u16*)(w8 + 2555904);
    a.HSH1 = (u16*)(w8 + 2686976);
    a.HSL1 = (u16*)(w8 + 2818048);
    a.XHI  = (u16*)(w8 + 2949120);
    a.XLO  = (u16*)(w8 + 3014656);
    u16* WIHHI = (u16*)(w8 + 3145728);
    u16* WIHLO = (u16*)(w8 + 6291456);
    u16* WHHHI = (u16*)(w8 + 9437184);
    u16* WHHLO = (u16*)(w8 + 15728640);
    u16* WOHI  = (u16*)(w8 + 22020096);
    u16* WOLO  = (u16*)(w8 + 87556096);
    a.wihhi = WIHHI; a.wihlo = WIHLO; a.whhhi = WHHHI; a.whhlo = WHHLO;
    a.wohi = WOHI; a.wolo = WOLO;

    const size_t NEED_FULL = 153092096;
    const bool ps = ws_size >= NEED_FULL;

    if (ps) {
        k_split_w<<<768,   256, 0, stream>>>(a.w_ih,  WIHHI, WIHLO, EMBD, 6, 3072 * (EMBD / 8));
        k_split_w<<<1536,  256, 0, stream>>>(a.w_hh,  WHHHI, WHHLO, HIDD, 7, 3072 * (HIDD / 8));
        k_split_w<<<16000, 256, 0, stream>>>(a.w_out, WOHI,  WOLO,  HIDD, 7, NVOC * (HIDD / 8));
    }

    void* kargs[] = { (void*)&a };
    hipError_t e = hipLaunchCooperativeKernel(
        ps ? reinterpret_cast<const void*>(&k_roll<true>)
           : reinterpret_cast<const void*>(&k_roll<false>),
        dim3(256), dim3(512), kargs, 0, stream);

    if (e != hipSuccess) {
        // fallback: multi-kernel path with identical numerics
        k_init_f<<<64, 512, 0, stream>>>(a);
        for (int t = 0; t < SEQL; ++t) {
            const int hi_ = t & 1, ho_ = hi_ ^ 1;
            if (ps) {
                k_gates_f<true><<<48, 512, 0, stream>>>(a, hi_);
                k_gru_f<<<128, 512, 0, stream>>>(a, hi_);
                k_logits_f<true><<<NLB, 512, 0, stream>>>(a, t, ho_);
            } else {
                k_gates_f<false><<<48, 512, 0, stream>>>(a, hi_);
                k_gru_f<<<128, 512, 0, stream>>>(a, hi_);
                k_logits_f<false><<<NLB, 512, 0, stream>>>(a, t, ho_);
            }
            k_sample_f<<<64, 512, 0, stream>>>(a, t);
        }
    }
}